// Round 4
// baseline (319.192 us; speedup 1.0000x reference)
//
#include <hip/hip_runtime.h>

typedef __attribute__((ext_vector_type(8))) short short8;    // bf16 frag
typedef __attribute__((ext_vector_type(8))) _Float16 half8;  // f16 frag
typedef __attribute__((ext_vector_type(4))) float f32x4;
typedef __attribute__((ext_vector_type(16))) float f32x16;
typedef __attribute__((ext_vector_type(4))) unsigned uint4v;
typedef __attribute__((ext_vector_type(2))) float float2v;

#define MFMA_BF16(a, b, c) __builtin_amdgcn_mfma_f32_16x16x32_bf16(a, b, c, 0, 0, 0)
#define MFMA32_BF16(a, b, c) __builtin_amdgcn_mfma_f32_32x32x16_bf16(a, b, c, 0, 0, 0)
#define MFMA32_F16(a, b, c) __builtin_amdgcn_mfma_f32_32x32x16_f16(a, b, c, 0, 0, 0)

#define GLD16(g, l)                                                          \
  __builtin_amdgcn_global_load_lds(                                          \
      (const __attribute__((address_space(1))) unsigned int*)(g),            \
      (__attribute__((address_space(3))) unsigned int*)(l), 16, 0, 0)

__device__ __forceinline__ unsigned short f2bf(float f) {
  unsigned int u = __float_as_uint(f);
  u += 0x7fffu + ((u >> 16) & 1u);
  return (unsigned short)(u >> 16);
}

// ---------------- merged prep: x->bf16 cvt + two weight transposes ----------------
// blocks [0,8192): cvt x (2M float4); [8192,8960): W_qkv 64x64 transpose tiles;
// [8960,9216): W_out tiles. One launch instead of three.
__global__ __launch_bounds__(256) void prep_k(const float* __restrict__ x,
                                              unsigned short* __restrict__ xb,
                                              const float* __restrict__ W_qkv,
                                              unsigned short* __restrict__ wqkvT,
                                              const float* __restrict__ W_out,
                                              unsigned short* __restrict__ woutT) {
  __shared__ float tile[64][65];
  const int blk = blockIdx.x;
  const int tid = threadIdx.x;
  if (blk < 8192) {
    int i = blk * 256 + tid;
    float4 v = reinterpret_cast<const float4*>(x)[i];
    ushort4 o;
    o.x = f2bf(v.x); o.y = f2bf(v.y); o.z = f2bf(v.z); o.w = f2bf(v.w);
    reinterpret_cast<ushort4*>(xb)[i] = o;
    return;
  }
  const float* W;
  unsigned short* Wt;
  int N, bx;
  if (blk < 8960) { W = W_qkv; Wt = wqkvT; N = 3072; bx = blk - 8192; }
  else            { W = W_out; Wt = woutT; N = 1024; bx = blk - 8960; }
  const int tk = (bx & 15) * 64;
  const int tn = (bx >> 4) * 64;
#pragma unroll
  for (int c = 0; c < 4; ++c) {
    int k = c * 16 + (tid >> 4);
    int n = (tid & 15) * 4;
    float4 v = *reinterpret_cast<const float4*>(&W[(size_t)(tk + k) * N + tn + n]);
    tile[k][n] = v.x; tile[k][n + 1] = v.y; tile[k][n + 2] = v.z; tile[k][n + 3] = v.w;
  }
  __syncthreads();
#pragma unroll
  for (int p = 0; p < 2; ++p) {
    int n = p * 32 + (tid >> 3);
    int k = (tid & 7) * 8;
    ushort4 a, b;
    a.x = f2bf(tile[k + 0][n]); a.y = f2bf(tile[k + 1][n]);
    a.z = f2bf(tile[k + 2][n]); a.w = f2bf(tile[k + 3][n]);
    b.x = f2bf(tile[k + 4][n]); b.y = f2bf(tile[k + 5][n]);
    b.z = f2bf(tile[k + 6][n]); b.w = f2bf(tile[k + 7][n]);
    *reinterpret_cast<ushort4*>(&Wt[(size_t)(tn + n) * 1024 + tk + k]) = a;
    *reinterpret_cast<ushort4*>(&Wt[(size_t)(tn + n) * 1024 + tk + k + 4]) = b;
  }
}

// ---------------- GEMM: C = A @ Bt^T + bias ----------------
// 128 x BN tile, BK=64, xor-swizzled LDS (slot = chunk ^ (row&7)).
template <int MODE, int BN>
__global__ __launch_bounds__(256) void gemm_bt(const unsigned short* __restrict__ A,
                                               const unsigned short* __restrict__ Bt,
                                               const float* __restrict__ bias,
                                               float* __restrict__ outF,
                                               unsigned short* __restrict__ q_ws,
                                               unsigned short* __restrict__ k_ws,
                                               unsigned short* __restrict__ vt_ws,
                                               int M, int N, int K) {
  constexpr int NJ = BN / 32;
  constexpr int NBC = BN * 64 / 2048;
  __shared__ unsigned short As[128 * 64];
  __shared__ unsigned short Bs[BN * 64];

  const int tid = threadIdx.x;
  const int wave = tid >> 6, lane = tid & 63;
  const int quad = lane >> 4, l15 = lane & 15;
  const int m0 = blockIdx.x * 128, n0 = blockIdx.y * BN;
  const int wm = (wave & 1) * 64, wn = (wave >> 1) * (BN / 2);

  const f32x4 zf = {0.f, 0.f, 0.f, 0.f};
  f32x4 acc[4][NJ];
#pragma unroll
  for (int i = 0; i < 4; ++i)
#pragma unroll
    for (int j = 0; j < NJ; ++j) acc[i][j] = zf;

  const int rr = tid >> 3;
  const int scol = ((tid & 7) ^ (rr & 7)) * 8;
  const int swz = l15 & 7;

  for (int kt = 0; kt < K; kt += 64) {
    __syncthreads();
#pragma unroll
    for (int c = 0; c < 4; ++c)
      GLD16(&A[(size_t)(m0 + c * 32 + rr) * K + kt + scol], &As[c * 2048 + tid * 8]);
#pragma unroll
    for (int c = 0; c < NBC; ++c)
      GLD16(&Bt[(size_t)(n0 + c * 32 + rr) * K + kt + scol], &Bs[c * 2048 + tid * 8]);
    __syncthreads();

#pragma unroll
    for (int kk = 0; kk < 2; ++kk) {
      const int ch = (kk * 4 + quad) ^ swz;
      short8 af[4], bg[NJ];
#pragma unroll
      for (int i = 0; i < 4; ++i)
        af[i] = *reinterpret_cast<const short8*>(&As[(wm + i * 16 + l15) * 64 + ch * 8]);
#pragma unroll
      for (int j = 0; j < NJ; ++j)
        bg[j] = *reinterpret_cast<const short8*>(&Bs[(wn + j * 16 + l15) * 64 + ch * 8]);
#pragma unroll
      for (int i = 0; i < 4; ++i)
#pragma unroll
        for (int j = 0; j < NJ; ++j) acc[i][j] = MFMA_BF16(af[i], bg[j], acc[i][j]);
    }
  }

  const float kScQ = 0.125f * 1.44269504088896f;  // log2(e)/sqrt(64)
  const int cls = n0 >> 10;
#pragma unroll
  for (int i = 0; i < 4; ++i) {
#pragma unroll
    for (int j = 0; j < NJ; ++j) {
      const int n = n0 + wn + j * 16 + l15;
      const float bv = bias[n];
      const int mb = m0 + wm + i * 16 + quad * 4;
      if (MODE == 1) {
#pragma unroll
        for (int r = 0; r < 4; ++r) outF[(size_t)(mb + r) * N + n] = acc[i][j][r] + bv;
      } else if (cls == 0) {
        const int b = mb >> 11, t0 = mb & 2047;
        const int h = n >> 6, d = n & 63;
#pragma unroll
        for (int r = 0; r < 4; ++r)
          q_ws[(((size_t)(b * 16 + h)) * 2048 + t0 + r) * 64 + d] =
              f2bf((acc[i][j][r] + bv) * kScQ);
      } else if (cls == 1) {
        const int b = mb >> 11, t0 = mb & 2047;
        const int n2 = n - 1024, h = n2 >> 6, d = n2 & 63;
#pragma unroll
        for (int r = 0; r < 4; ++r)
          k_ws[(((size_t)(b * 16 + h)) * 2048 + t0 + r) * 64 + d] = f2bf(acc[i][j][r] + bv);
      } else {
        const int b = mb >> 11, t0 = mb & 2047;
        const int n2 = n - 2048, h = n2 >> 6, d = n2 & 63;
        uint2 pk;
        pk.x = __builtin_bit_cast(unsigned int,
                                  __builtin_amdgcn_cvt_pkrtz(acc[i][j][0] + bv, acc[i][j][1] + bv));
        pk.y = __builtin_bit_cast(unsigned int,
                                  __builtin_amdgcn_cvt_pkrtz(acc[i][j][2] + bv, acc[i][j][3] + bv));
        *reinterpret_cast<uint2*>(
            &vt_ws[(((size_t)(b * 16 + h)) * 64 + d) * 2048 + t0]) = pk;
      }
    }
  }
}

// ---------------- flash attention: barrier-free, LDS-free, direct-L2 streaming ----
// Q,K: [B*H, T, 64] bf16 (Q pre-scaled, log2 domain); Vt: [B*H, 64, T] fp16.
// K/V per head = 512KB; with the head->XCD swizzle each XCD's L2 working set is
// exactly 8 heads x 512KB = 4MB, so K/V is L2-resident (measured: FETCH 31MB vs
// ~280MB demand). LDS staging therefore only bought the lockstep convoy (2
// barriers + vmcnt(0)-equivalent per tile, all waves slamming LDS together) —
// established by r1-r3 A/Bs: conflicts -33% flat, waves x2 worse, interleave flat.
// This version: each wave streams its own K/V fragments global->VGPR
// (16B/lane global_load_dwordx4, L2-hit), per-wave trip count, zero sync.
// Compiler inserts counted per-use vmcnt; V-pair loads issue early so latency
// hides under QK/softmax. Waves desynchronize freely.
// 32x32x16 layouts: A/B m|n=lane&31, k=(lane>>5)*8+j;
// C/D col=lane&31, row=(reg&3)+8*(reg>>2)+4*(lane>>5).
__global__ __launch_bounds__(256, 3) void attn_k(const unsigned short* __restrict__ q_ws,
                                                 const unsigned short* __restrict__ k_ws,
                                                 const unsigned short* __restrict__ vt_ws,
                                                 unsigned short* __restrict__ att_ws) {
  const int T = 2048;
  const int bid = blockIdx.x;
  const int bh = (bid & 7) * 8 + ((bid >> 3) & 7);  // XCD-locality swizzle
  const int s = 15 - (bid >> 6);                    // heaviest strips first
  const int tid = threadIdx.x;
  const int wv = tid >> 6, lane = tid & 63;
  const int L = lane & 31, hl = lane >> 5;

  const unsigned short* Qh = q_ws + (size_t)bh * T * 64;
  const unsigned short* Kh = k_ws + (size_t)bh * T * 64;
  const _Float16* Vh = (const _Float16*)vt_ws + (size_t)bh * 64 * T;
  const int b = bh >> 4, h = bh & 15;

  const int qw = s * 4 + wv;     // 32-query tile index 0..63
  const int q0 = qw * 32;
  const int diagTile = qw >> 1;  // last 64-key tile this wave needs
  const int myq = q0 + L;

  // Q B-frags for 4 k-steps: B[n=q][k=kk*16+hl*8+j]
  short8 qb[4];
#pragma unroll
  for (int kk = 0; kk < 4; ++kk)
    qb[kk] = *reinterpret_cast<const short8*>(&Qh[(size_t)(q0 + L) * 64 + kk * 16 + hl * 8]);

  f32x16 o0 = {}, o1 = {};
  float2v li = {0.f, 0.f};

  // per-lane base pointers for register-fragment loads
  const unsigned short* Kp0 = Kh + (size_t)L * 64 + hl * 8;         // key rows L
  const unsigned short* Kp1 = Kh + (size_t)(32 + L) * 64 + hl * 8;  // key rows 32+L
  const _Float16* Vp0 = Vh + (size_t)L * T + hl * 8;                // dim rows L
  const _Float16* Vp1 = Vh + (size_t)(32 + L) * T + hl * 8;         // dim rows 32+L

  // softmax half-pipeline: exp2 + l_i (packed adds) + f16 pack + in-reg transpose
  auto softmax32 = [&](const f32x16& scc, unsigned (&pwc)[4][2]) {
#pragma unroll
    for (int g = 0; g < 4; ++g) {
      float2v e01, e23;
      e01[0] = exp2f(scc[4 * g + 0]);
      e01[1] = exp2f(scc[4 * g + 1]);
      e23[0] = exp2f(scc[4 * g + 2]);
      e23[1] = exp2f(scc[4 * g + 3]);
      float2v s2;
      asm("v_pk_add_f32 %0, %1, %2" : "=v"(s2) : "v"(e01), "v"(e23));
      asm("v_pk_add_f32 %0, %0, %1" : "+v"(li) : "v"(s2));
      pwc[g][0] = __builtin_bit_cast(unsigned int, __builtin_amdgcn_cvt_pkrtz(e01[0], e01[1]));
      pwc[g][1] = __builtin_bit_cast(unsigned int, __builtin_amdgcn_cvt_pkrtz(e23[0], e23[1]));
    }
    // v_permlane32_swap: frag(t)=[w(2t,0),w(2t,1),w(2t+1,0),w(2t+1,1)] then holds
    // keys t*16+hl*8+0..7 in order for BOTH hl halves.
#pragma unroll
    for (int r = 0; r < 2; ++r) {
      asm volatile("v_permlane32_swap_b32 %0, %1" : "+v"(pwc[0][r]), "+v"(pwc[1][r]));
      asm volatile("v_permlane32_swap_b32 %0, %1" : "+v"(pwc[2][r]), "+v"(pwc[3][r]));
    }
  };

  for (int kt = 0; kt <= diagTile; ++kt) {
    const int kb = kt * 64;

    // K fragments for this 64-key tile (8 x 16B, L2-hit) + first V pair
    short8 kf0[4], kf1[4];
#pragma unroll
    for (int kk = 0; kk < 4; ++kk) {
      kf0[kk] = *reinterpret_cast<const short8*>(Kp0 + (size_t)kb * 64 + kk * 16);
      kf1[kk] = *reinterpret_cast<const short8*>(Kp1 + (size_t)kb * 64 + kk * 16);
    }
    half8 v00 = *reinterpret_cast<const half8*>(Vp0 + kb);        // t=0, dims L
    half8 v10 = *reinterpret_cast<const half8*>(Vp1 + kb);        // t=0, dims 32+L
    half8 v01 = *reinterpret_cast<const half8*>(Vp0 + kb + 16);   // t=1
    half8 v11 = *reinterpret_cast<const half8*>(Vp1 + kb + 16);

    // S^T = K·Q^T, two 32-key tiles
    f32x16 sc0 = {}, sc1 = {};
    __builtin_amdgcn_s_setprio(1);
#pragma unroll
    for (int kk = 0; kk < 4; ++kk) {
      sc0 = MFMA32_BF16(kf0[kk], qb[kk], sc0);
      sc1 = MFMA32_BF16(kf1[kk], qb[kk], sc1);
    }
    __builtin_amdgcn_s_setprio(0);

    // second V pair (t=2,3): latency hides under sm0 + PV0
    half8 v02 = *reinterpret_cast<const half8*>(Vp0 + kb + 32);
    half8 v12 = *reinterpret_cast<const half8*>(Vp1 + kb + 32);
    half8 v03 = *reinterpret_cast<const half8*>(Vp0 + kb + 48);
    half8 v13 = *reinterpret_cast<const half8*>(Vp1 + kb + 48);

    if (kt == diagTile) {  // causal mask, low half
#pragma unroll
      for (int reg = 0; reg < 16; ++reg) {
        const int row = (reg & 3) + 8 * (reg >> 2) + 4 * hl;
        sc0[reg] = (kb + row > myq) ? -1e30f : sc0[reg];
      }
    }
    unsigned pw0[4][2], pw1[4][2];
    softmax32(sc0, pw0);

    // PV pair 0 (keys kb..kb+31)
    __builtin_amdgcn_s_setprio(1);
    {
      uint4v f0 = {pw0[0][0], pw0[0][1], pw0[1][0], pw0[1][1]};
      uint4v f1 = {pw0[2][0], pw0[2][1], pw0[3][0], pw0[3][1]};
      half8 pb0 = __builtin_bit_cast(half8, f0);
      half8 pb1 = __builtin_bit_cast(half8, f1);
      o0 = MFMA32_F16(v00, pb0, o0);
      o1 = MFMA32_F16(v10, pb0, o1);
      o0 = MFMA32_F16(v01, pb1, o0);
      o1 = MFMA32_F16(v11, pb1, o1);
    }
    __builtin_amdgcn_s_setprio(0);

    if (kt == diagTile) {  // causal mask, high half
#pragma unroll
      for (int reg = 0; reg < 16; ++reg) {
        const int row = (reg & 3) + 8 * (reg >> 2) + 4 * hl;
        sc1[reg] = (kb + 32 + row > myq) ? -1e30f : sc1[reg];
      }
    }
    softmax32(sc1, pw1);

    // PV pair 1 (keys kb+32..kb+63)
    __builtin_amdgcn_s_setprio(1);
    {
      uint4v f0 = {pw1[0][0], pw1[0][1], pw1[1][0], pw1[1][1]};
      uint4v f1 = {pw1[2][0], pw1[2][1], pw1[3][0], pw1[3][1]};
      half8 pb0 = __builtin_bit_cast(half8, f0);
      half8 pb1 = __builtin_bit_cast(half8, f1);
      o0 = MFMA32_F16(v02, pb0, o0);
      o1 = MFMA32_F16(v12, pb0, o1);
      o0 = MFMA32_F16(v03, pb1, o0);
      o1 = MFMA32_F16(v13, pb1, o1);
    }
    __builtin_amdgcn_s_setprio(0);
  }

  float l_i = li[0] + li[1];
  l_i += __shfl_xor(l_i, 32);
  const float inv = 1.f / l_i;
#pragma unroll
  for (int sg = 0; sg < 2; ++sg) {
    const f32x16& oo = sg ? o1 : o0;
#pragma unroll
    for (int g = 0; g < 4; ++g) {
      const int d0 = sg * 32 + g * 8 + hl * 4;  // 4 consecutive dims
      uint2 ov;
      ov.x = (unsigned)f2bf(oo[4 * g + 0] * inv) | ((unsigned)f2bf(oo[4 * g + 1] * inv) << 16);
      ov.y = (unsigned)f2bf(oo[4 * g + 2] * inv) | ((unsigned)f2bf(oo[4 * g + 3] * inv) << 16);
      *reinterpret_cast<uint2*>(
          &att_ws[(size_t)(b * 2048 + q0 + L) * 1024 + h * 64 + d0]) = ov;
    }
  }
}

// ---------------- launch ----------------
extern "C" void kernel_launch(void* const* d_in, const int* in_sizes, int n_in,
                              void* d_out, int out_size, void* d_ws, size_t ws_size,
                              hipStream_t stream) {
  (void)in_sizes; (void)n_in; (void)out_size; (void)ws_size;
  const float* x     = (const float*)d_in[0];
  const float* W_qkv = (const float*)d_in[1];
  const float* b_qkv = (const float*)d_in[2];
  const float* W_out = (const float*)d_in[3];
  const float* b_out = (const float*)d_in[4];
  float* out = (float*)d_out;

  char* ws = (char*)d_ws;
  unsigned short* xb    = (unsigned short*)(ws);
  unsigned short* wqkvT = (unsigned short*)(ws + 16777216);
  unsigned short* woutT = (unsigned short*)(ws + 23068672);
  unsigned short* q_ws  = (unsigned short*)(ws + 25165824);
  unsigned short* k_ws  = (unsigned short*)(ws + 41943040);
  unsigned short* vt_ws = (unsigned short*)(ws + 58720256);
  unsigned short* attb  = (unsigned short*)(ws + 75497472);

  prep_k<<<9216, 256, 0, stream>>>(x, xb, W_qkv, wqkvT, W_out, woutT);

  dim3 g1(64, 24);
  gemm_bt<0, 128><<<g1, 256, 0, stream>>>(xb, wqkvT, b_qkv, nullptr, q_ws, k_ws, vt_ws,
                                          8192, 3072, 1024);
  attn_k<<<1024, 256, 0, stream>>>(q_ws, k_ws, vt_ws, attb);

  dim3 g2(64, 16);
  gemm_bt<1, 64><<<g2, 256, 0, stream>>>(attb, woutT, b_out, out, nullptr, nullptr, nullptr,
                                         8192, 1024, 1024);
}

// Round 5
// 246.056 us; speedup vs baseline: 1.2972x; 1.2972x over previous
//
#include <hip/hip_runtime.h>

typedef __attribute__((ext_vector_type(8))) short short8;    // bf16 frag
typedef __attribute__((ext_vector_type(8))) _Float16 half8;  // f16 frag
typedef __attribute__((ext_vector_type(4))) float f32x4;
typedef __attribute__((ext_vector_type(16))) float f32x16;
typedef __attribute__((ext_vector_type(4))) unsigned uint4v;
typedef __attribute__((ext_vector_type(2))) float float2v;

#define MFMA_BF16(a, b, c) __builtin_amdgcn_mfma_f32_16x16x32_bf16(a, b, c, 0, 0, 0)
#define MFMA32_BF16(a, b, c) __builtin_amdgcn_mfma_f32_32x32x16_bf16(a, b, c, 0, 0, 0)
#define MFMA32_F16(a, b, c) __builtin_amdgcn_mfma_f32_32x32x16_f16(a, b, c, 0, 0, 0)

#define GLD16(g, l)                                                          \
  __builtin_amdgcn_global_load_lds(                                          \
      (const __attribute__((address_space(1))) unsigned int*)(g),            \
      (__attribute__((address_space(3))) unsigned int*)(l), 16, 0, 0)

__device__ __forceinline__ unsigned short f2bf(float f) {
  unsigned int u = __float_as_uint(f);
  u += 0x7fffu + ((u >> 16) & 1u);
  return (unsigned short)(u >> 16);
}

// ---------------- merged prep: x->bf16 cvt + two weight transposes ----------------
__global__ __launch_bounds__(256) void prep_k(const float* __restrict__ x,
                                              unsigned short* __restrict__ xb,
                                              const float* __restrict__ W_qkv,
                                              unsigned short* __restrict__ wqkvT,
                                              const float* __restrict__ W_out,
                                              unsigned short* __restrict__ woutT) {
  __shared__ float tile[64][65];
  const int blk = blockIdx.x;
  const int tid = threadIdx.x;
  if (blk < 8192) {
    int i = blk * 256 + tid;
    float4 v = reinterpret_cast<const float4*>(x)[i];
    ushort4 o;
    o.x = f2bf(v.x); o.y = f2bf(v.y); o.z = f2bf(v.z); o.w = f2bf(v.w);
    reinterpret_cast<ushort4*>(xb)[i] = o;
    return;
  }
  const float* W;
  unsigned short* Wt;
  int N, bx;
  if (blk < 8960) { W = W_qkv; Wt = wqkvT; N = 3072; bx = blk - 8192; }
  else            { W = W_out; Wt = woutT; N = 1024; bx = blk - 8960; }
  const int tk = (bx & 15) * 64;
  const int tn = (bx >> 4) * 64;
#pragma unroll
  for (int c = 0; c < 4; ++c) {
    int k = c * 16 + (tid >> 4);
    int n = (tid & 15) * 4;
    float4 v = *reinterpret_cast<const float4*>(&W[(size_t)(tk + k) * N + tn + n]);
    tile[k][n] = v.x; tile[k][n + 1] = v.y; tile[k][n + 2] = v.z; tile[k][n + 3] = v.w;
  }
  __syncthreads();
#pragma unroll
  for (int p = 0; p < 2; ++p) {
    int n = p * 32 + (tid >> 3);
    int k = (tid & 7) * 8;
    ushort4 a, b;
    a.x = f2bf(tile[k + 0][n]); a.y = f2bf(tile[k + 1][n]);
    a.z = f2bf(tile[k + 2][n]); a.w = f2bf(tile[k + 3][n]);
    b.x = f2bf(tile[k + 4][n]); b.y = f2bf(tile[k + 5][n]);
    b.z = f2bf(tile[k + 6][n]); b.w = f2bf(tile[k + 7][n]);
    *reinterpret_cast<ushort4*>(&Wt[(size_t)(tn + n) * 1024 + tk + k]) = a;
    *reinterpret_cast<ushort4*>(&Wt[(size_t)(tn + n) * 1024 + tk + k + 4]) = b;
  }
}

// ---------------- 8-wave dbuf GEMM: C = A @ Bt^T + bias (T3+T4 schedule) ----------
// BM=128, BN=256, BK=64, 512 thr (8 waves, 2M x 4N, 64x64 per wave).
// Double-buffered LDS (96KB), counted vmcnt(6) — prefetch of tile t+1 stays in
// flight across the barrier while tile t computes (never drains to 0 in-loop).
// Two 16-MFMA phases per K-tile (kk=0/1), phase barriers keep waves aligned so
// LDS-read bursts and MFMA bursts from different waves overlap; s_setprio wraps
// each MFMA cluster. Same xor-swizzled staging/fragment scheme as the verified
// 128x128 kernel (slot = chunk ^ (row&7); 0 bank conflicts measured).
template <int MODE>
__global__ __launch_bounds__(512, 2) void gemm8(const unsigned short* __restrict__ A,
                                                const unsigned short* __restrict__ Bt,
                                                const float* __restrict__ bias,
                                                float* __restrict__ outF,
                                                unsigned short* __restrict__ q_ws,
                                                unsigned short* __restrict__ k_ws,
                                                unsigned short* __restrict__ vt_ws,
                                                int N) {
  constexpr int K = 1024;
  __shared__ unsigned short As[2][128 * 64];  // 32KB
  __shared__ unsigned short Bs[2][256 * 64];  // 64KB
  const int tid = threadIdx.x;
  const int wave = tid >> 6, lane = tid & 63;
  const int quad = lane >> 4, l15 = lane & 15;
  const int m0 = blockIdx.x * 128, n0 = blockIdx.y * 256;
  const int wm = (wave & 1) * 64, wn = (wave >> 1) * 64;

  const f32x4 zf = {0.f, 0.f, 0.f, 0.f};
  f32x4 acc[4][4];
#pragma unroll
  for (int i = 0; i < 4; ++i)
#pragma unroll
    for (int j = 0; j < 4; ++j) acc[i][j] = zf;

  // staging: 512 thr; row = c*64 + (tid>>3), slot = tid&7; source chunk xor'd
  // so readers find data chunk ck of row r at slot ck^(r&7).
  const int rr = tid >> 3;
  const int scol = ((tid & 7) ^ (rr & 7)) * 8;
  const int swz = l15 & 7;
  const unsigned short* Arow = &A[(size_t)(m0 + rr) * K + scol];
  const unsigned short* Brow = &Bt[(size_t)(n0 + rr) * K + scol];

  // prologue: stage K-tile 0 into buf 0 (6 GLD16 in flight)
#pragma unroll
  for (int c = 0; c < 2; ++c)
    GLD16(Arow + (size_t)c * 64 * K, &As[0][c * 4096 + tid * 8]);
#pragma unroll
  for (int c = 0; c < 4; ++c)
    GLD16(Brow + (size_t)c * 64 * K, &Bs[0][c * 4096 + tid * 8]);

  for (int t = 0; t < 16; ++t) {
    const int cur = t & 1, nxt = cur ^ 1;
    const int pf = (t < 15) ? (t + 1) : 15;  // uniform vmcnt; tail re-stage harmless
    const size_t ko = (size_t)pf * 64;
    // issue next tile's 6 loads (into nxt: all waves past last read of it at the
    // loop-carried end-of-iteration barrier)
#pragma unroll
    for (int c = 0; c < 2; ++c)
      GLD16(Arow + (size_t)c * 64 * K + ko, &As[nxt][c * 4096 + tid * 8]);
#pragma unroll
    for (int c = 0; c < 4; ++c)
      GLD16(Brow + (size_t)c * 64 * K + ko, &Bs[nxt][c * 4096 + tid * 8]);
    // wait only for cur's 6 (issued last iteration); the 6 new stay in flight
    asm volatile("s_waitcnt vmcnt(6)\n\ts_barrier" ::: "memory");

#pragma unroll
    for (int kk = 0; kk < 2; ++kk) {
      const int ch = (kk * 4 + quad) ^ swz;
      short8 af[4], bg[4];
#pragma unroll
      for (int i = 0; i < 4; ++i)
        af[i] = *reinterpret_cast<const short8*>(&As[cur][(wm + i * 16 + l15) * 64 + ch * 8]);
#pragma unroll
      for (int j = 0; j < 4; ++j)
        bg[j] = *reinterpret_cast<const short8*>(&Bs[cur][(wn + j * 16 + l15) * 64 + ch * 8]);
      __builtin_amdgcn_s_setprio(1);
#pragma unroll
      for (int i = 0; i < 4; ++i)
#pragma unroll
        for (int j = 0; j < 4; ++j) acc[i][j] = MFMA_BF16(af[i], bg[j], acc[i][j]);
      __builtin_amdgcn_s_setprio(0);
      asm volatile("s_barrier" ::: "memory");  // phase / end-of-iter barrier
    }
  }
  // drain prefetch before exit (outstanding GLD would corrupt successor's LDS)
  asm volatile("s_waitcnt vmcnt(0)" ::: "memory");

  const float kScQ = 0.125f * 1.44269504088896f;  // log2(e)/sqrt(64)
  const int cls = n0 >> 10;
#pragma unroll
  for (int i = 0; i < 4; ++i) {
#pragma unroll
    for (int j = 0; j < 4; ++j) {
      const int n = n0 + wn + j * 16 + l15;
      const float bv = bias[n];
      const int mb = m0 + wm + i * 16 + quad * 4;
      if (MODE == 1) {
#pragma unroll
        for (int r = 0; r < 4; ++r) outF[(size_t)(mb + r) * N + n] = acc[i][j][r] + bv;
      } else if (cls == 0) {
        const int b = mb >> 11, t0 = mb & 2047;
        const int h = n >> 6, d = n & 63;
#pragma unroll
        for (int r = 0; r < 4; ++r)
          q_ws[(((size_t)(b * 16 + h)) * 2048 + t0 + r) * 64 + d] =
              f2bf((acc[i][j][r] + bv) * kScQ);
      } else if (cls == 1) {
        const int b = mb >> 11, t0 = mb & 2047;
        const int n2 = n - 1024, h = n2 >> 6, d = n2 & 63;
#pragma unroll
        for (int r = 0; r < 4; ++r)
          k_ws[(((size_t)(b * 16 + h)) * 2048 + t0 + r) * 64 + d] = f2bf(acc[i][j][r] + bv);
      } else {
        const int b = mb >> 11, t0 = mb & 2047;
        const int n2 = n - 2048, h = n2 >> 6, d = n2 & 63;
        uint2 pk;
        pk.x = __builtin_bit_cast(unsigned int,
                                  __builtin_amdgcn_cvt_pkrtz(acc[i][j][0] + bv, acc[i][j][1] + bv));
        pk.y = __builtin_bit_cast(unsigned int,
                                  __builtin_amdgcn_cvt_pkrtz(acc[i][j][2] + bv, acc[i][j][3] + bv));
        *reinterpret_cast<uint2*>(
            &vt_ws[(((size_t)(b * 16 + h)) * 64 + d) * 2048 + t0]) = pk;
      }
    }
  }
}

// ---------------- flash attention: 32x32 MFMA, 4 waves, split softmax/PV pipeline ----
// (r3 structure — best measured variant; direct-L2 r4 variant was 2.1x worse.)
// Q,K: [B*H, T, 64] bf16 (Q pre-scaled, log2 domain); Vt: [B*H, 64, T] fp16.
__global__ __launch_bounds__(256, 3) void attn_k(const unsigned short* __restrict__ q_ws,
                                                 const unsigned short* __restrict__ k_ws,
                                                 const unsigned short* __restrict__ vt_ws,
                                                 unsigned short* __restrict__ att_ws) {
  const int T = 2048;
  const int bid = blockIdx.x;
  const int bh = (bid & 7) * 8 + ((bid >> 3) & 7);  // XCD-locality swizzle
  const int s = 15 - (bid >> 6);                    // heaviest strips first (LPT)
  const int tid = threadIdx.x;
  const int wv = tid >> 6, lane = tid & 63;
  const int L = lane & 31, hl = lane >> 5;

  const unsigned short* Qh = q_ws + (size_t)bh * T * 64;
  const unsigned short* Kh = k_ws + (size_t)bh * T * 64;
  const _Float16* Vh = (const _Float16*)vt_ws + (size_t)bh * 64 * T;
  const int b = bh >> 4, h = bh & 15;

  __shared__ unsigned short Ks[2][64 * 64];  // dbuf, xor-swizzled 8-elem chunks
  __shared__ _Float16 Vs[2][64 * 64];

  const int qw = s * 4 + wv;     // 32-query tile index 0..63
  const int q0 = qw * 32;
  const int diagTile = qw >> 1;  // last 64-key tile this wave needs
  const int nk = 2 * s + 2;      // block-uniform trip count
  const int myq = q0 + L;

  short8 qb[4];
#pragma unroll
  for (int kk = 0; kk < 4; ++kk)
    qb[kk] = *reinterpret_cast<const short8*>(&Qh[(size_t)(q0 + L) * 64 + kk * 16 + hl * 8]);

  f32x16 o0 = {}, o1 = {};
  float2v li = {0.f, 0.f};

  const int srow8 = tid >> 3;
  const int schunk = (tid & 7) ^ (srow8 & 7);

  GLD16(&Kh[(size_t)srow8 * 64 + schunk * 8], &Ks[0][tid * 8]);
  GLD16(&Kh[(size_t)(32 + srow8) * 64 + schunk * 8], &Ks[0][2048 + tid * 8]);
  GLD16(&Vh[(size_t)srow8 * T + schunk * 8], &Vs[0][tid * 8]);
  GLD16(&Vh[(size_t)(32 + srow8) * T + schunk * 8], &Vs[0][2048 + tid * 8]);

  auto softmax32 = [&](const f32x16& scc, unsigned (&pwc)[4][2]) {
#pragma unroll
    for (int g = 0; g < 4; ++g) {
      float2v e01, e23;
      e01[0] = __builtin_amdgcn_exp2f(scc[4 * g + 0]);
      e01[1] = __builtin_amdgcn_exp2f(scc[4 * g + 1]);
      e23[0] = __builtin_amdgcn_exp2f(scc[4 * g + 2]);
      e23[1] = __builtin_amdgcn_exp2f(scc[4 * g + 3]);
      float2v s2;
      asm("v_pk_add_f32 %0, %1, %2" : "=v"(s2) : "v"(e01), "v"(e23));
      asm("v_pk_add_f32 %0, %0, %1" : "+v"(li) : "v"(s2));
      pwc[g][0] = __builtin_bit_cast(unsigned int, __builtin_amdgcn_cvt_pkrtz(e01[0], e01[1]));
      pwc[g][1] = __builtin_bit_cast(unsigned int, __builtin_amdgcn_cvt_pkrtz(e23[0], e23[1]));
    }
#pragma unroll
    for (int r = 0; r < 2; ++r) {
      asm volatile("v_permlane32_swap_b32 %0, %1" : "+v"(pwc[0][r]), "+v"(pwc[1][r]));
      asm volatile("v_permlane32_swap_b32 %0, %1" : "+v"(pwc[2][r]), "+v"(pwc[3][r]));
    }
  };

  for (int kt = 0; kt < nk; ++kt) {
    const int cur = kt & 1, nxt = cur ^ 1;
    if (kt) asm volatile("s_barrier" ::: "memory");  // all waves done with buf[nxt]
    const int pf = (kt + 1 < nk) ? kt + 1 : nk - 1;
    GLD16(&Kh[(size_t)(pf * 64 + srow8) * 64 + schunk * 8], &Ks[nxt][tid * 8]);
    GLD16(&Kh[(size_t)(pf * 64 + 32 + srow8) * 64 + schunk * 8], &Ks[nxt][2048 + tid * 8]);
    GLD16(&Vh[(size_t)srow8 * T + pf * 64 + schunk * 8], &Vs[nxt][tid * 8]);
    GLD16(&Vh[(size_t)(32 + srow8) * T + pf * 64 + schunk * 8], &Vs[nxt][2048 + tid * 8]);
    asm volatile("s_waitcnt vmcnt(4)\n\ts_barrier" ::: "memory");

    if (kt <= diagTile) {
      const unsigned short* KsC = Ks[cur];
      const _Float16* VsC = Vs[cur];
      const int kb = kt * 64;

      f32x16 sc0 = {}, sc1 = {};
      __builtin_amdgcn_s_setprio(1);
#pragma unroll
      for (int kk = 0; kk < 4; ++kk) {
        const int sl = ((kk * 2 + hl) ^ (L & 7)) * 8;
        short8 k0 = *reinterpret_cast<const short8*>(&KsC[L * 64 + sl]);
        short8 k1 = *reinterpret_cast<const short8*>(&KsC[(32 + L) * 64 + sl]);
        sc0 = MFMA32_BF16(k0, qb[kk], sc0);
        sc1 = MFMA32_BF16(k1, qb[kk], sc1);
      }
      __builtin_amdgcn_s_setprio(0);

      half8 vr0[2], vr1[2];
#pragma unroll
      for (int t = 0; t < 2; ++t) {
        const int sl = ((t * 2 + hl) ^ (L & 7)) * 8;
        vr0[t] = *reinterpret_cast<const half8*>(&VsC[L * 64 + sl]);
        vr1[t] = *reinterpret_cast<const half8*>(&VsC[(32 + L) * 64 + sl]);
      }

      if (kt == diagTile) {
#pragma unroll
        for (int reg = 0; reg < 16; ++reg) {
          const int row = (reg & 3) + 8 * (reg >> 2) + 4 * hl;
          sc0[reg] = (kb + row > myq) ? -1e30f : sc0[reg];
        }
      }
      unsigned pw0[4][2], pw1[4][2];
      softmax32(sc0, pw0);

      half8 vr2[2], vr3[2];
#pragma unroll
      for (int t = 2; t < 4; ++t) {
        const int sl = ((t * 2 + hl) ^ (L & 7)) * 8;
        vr2[t - 2] = *reinterpret_cast<const half8*>(&VsC[L * 64 + sl]);
        vr3[t - 2] = *reinterpret_cast<const half8*>(&VsC[(32 + L) * 64 + sl]);
      }

      __builtin_amdgcn_s_setprio(1);
      {
        uint4v f0 = {pw0[0][0], pw0[0][1], pw0[1][0], pw0[1][1]};
        uint4v f1 = {pw0[2][0], pw0[2][1], pw0[3][0], pw0[3][1]};
        half8 pb0 = __builtin_bit_cast(half8, f0);
        half8 pb1 = __builtin_bit_cast(half8, f1);
        o0 = MFMA32_F16(vr0[0], pb0, o0);
        o1 = MFMA32_F16(vr1[0], pb0, o1);
        o0 = MFMA32_F16(vr0[1], pb1, o0);
        o1 = MFMA32_F16(vr1[1], pb1, o1);
      }
      __builtin_amdgcn_s_setprio(0);

      if (kt == diagTile) {
#pragma unroll
        for (int reg = 0; reg < 16; ++reg) {
          const int row = (reg & 3) + 8 * (reg >> 2) + 4 * hl;
          sc1[reg] = (kb + 32 + row > myq) ? -1e30f : sc1[reg];
        }
      }
      softmax32(sc1, pw1);

      __builtin_amdgcn_s_setprio(1);
      {
        uint4v f0 = {pw1[0][0], pw1[0][1], pw1[1][0], pw1[1][1]};
        uint4v f1 = {pw1[2][0], pw1[2][1], pw1[3][0], pw1[3][1]};
        half8 pb0 = __builtin_bit_cast(half8, f0);
        half8 pb1 = __builtin_bit_cast(half8, f1);
        o0 = MFMA32_F16(vr2[0], pb0, o0);
        o1 = MFMA32_F16(vr3[0], pb0, o1);
        o0 = MFMA32_F16(vr2[1], pb1, o0);
        o1 = MFMA32_F16(vr3[1], pb1, o1);
      }
      __builtin_amdgcn_s_setprio(0);
    }
  }
  asm volatile("s_waitcnt vmcnt(0)" ::: "memory");

  float l_i = li[0] + li[1];
  l_i += __shfl_xor(l_i, 32);
  const float inv = 1.f / l_i;
#pragma unroll
  for (int sg = 0; sg < 2; ++sg) {
    const f32x16& oo = sg ? o1 : o0;
#pragma unroll
    for (int g = 0; g < 4; ++g) {
      const int d0 = sg * 32 + g * 8 + hl * 4;
      uint2 ov;
      ov.x = (unsigned)f2bf(oo[4 * g + 0] * inv) | ((unsigned)f2bf(oo[4 * g + 1] * inv) << 16);
      ov.y = (unsigned)f2bf(oo[4 * g + 2] * inv) | ((unsigned)f2bf(oo[4 * g + 3] * inv) << 16);
      *reinterpret_cast<uint2*>(
          &att_ws[(size_t)(b * 2048 + q0 + L) * 1024 + h * 64 + d0]) = ov;
    }
  }
}

// ---------------- launch ----------------
extern "C" void kernel_launch(void* const* d_in, const int* in_sizes, int n_in,
                              void* d_out, int out_size, void* d_ws, size_t ws_size,
                              hipStream_t stream) {
  (void)in_sizes; (void)n_in; (void)out_size; (void)ws_size;
  const float* x     = (const float*)d_in[0];
  const float* W_qkv = (const float*)d_in[1];
  const float* b_qkv = (const float*)d_in[2];
  const float* W_out = (const float*)d_in[3];
  const float* b_out = (const float*)d_in[4];
  float* out = (float*)d_out;

  char* ws = (char*)d_ws;
  unsigned short* xb    = (unsigned short*)(ws);
  unsigned short* wqkvT = (unsigned short*)(ws + 16777216);
  unsigned short* woutT = (unsigned short*)(ws + 23068672);
  unsigned short* q_ws  = (unsigned short*)(ws + 25165824);
  unsigned short* k_ws  = (unsigned short*)(ws + 41943040);
  unsigned short* vt_ws = (unsigned short*)(ws + 58720256);
  unsigned short* attb  = (unsigned short*)(ws + 75497472);

  prep_k<<<9216, 256, 0, stream>>>(x, xb, W_qkv, wqkvT, W_out, woutT);

  dim3 g1(64, 12);  // 768 blocks = 3 clean rounds/CU
  gemm8<0><<<g1, 512, 0, stream>>>(xb, wqkvT, b_qkv, nullptr, q_ws, k_ws, vt_ws, 3072);

  attn_k<<<1024, 256, 0, stream>>>(q_ws, k_ws, vt_ws, attb);

  dim3 g2(64, 4);   // 256 blocks = exactly 1/CU
  gemm8<1><<<g2, 512, 0, stream>>>(attb, woutT, b_out, out, nullptr, nullptr, nullptr, 1024);
}

// Round 6
// 245.179 us; speedup vs baseline: 1.3019x; 1.0036x over previous
//
#include <hip/hip_runtime.h>

typedef __attribute__((ext_vector_type(8))) short short8;    // bf16 frag
typedef __attribute__((ext_vector_type(8))) _Float16 half8;  // f16 frag
typedef __attribute__((ext_vector_type(4))) float f32x4;
typedef __attribute__((ext_vector_type(16))) float f32x16;
typedef __attribute__((ext_vector_type(4))) unsigned uint4v;
typedef __attribute__((ext_vector_type(2))) float float2v;

#define MFMA_BF16(a, b, c) __builtin_amdgcn_mfma_f32_16x16x32_bf16(a, b, c, 0, 0, 0)
#define MFMA32_BF16(a, b, c) __builtin_amdgcn_mfma_f32_32x32x16_bf16(a, b, c, 0, 0, 0)
#define MFMA32_F16(a, b, c) __builtin_amdgcn_mfma_f32_32x32x16_f16(a, b, c, 0, 0, 0)

#define GLD16(g, l)                                                          \
  __builtin_amdgcn_global_load_lds(                                          \
      (const __attribute__((address_space(1))) unsigned int*)(g),            \
      (__attribute__((address_space(3))) unsigned int*)(l), 16, 0, 0)

__device__ __forceinline__ unsigned short f2bf(float f) {
  unsigned int u = __float_as_uint(f);
  u += 0x7fffu + ((u >> 16) & 1u);
  return (unsigned short)(u >> 16);
}

// ---------------- merged prep: x->bf16 cvt + two weight transposes ----------------
__global__ __launch_bounds__(256) void prep_k(const float* __restrict__ x,
                                              unsigned short* __restrict__ xb,
                                              const float* __restrict__ W_qkv,
                                              unsigned short* __restrict__ wqkvT,
                                              const float* __restrict__ W_out,
                                              unsigned short* __restrict__ woutT) {
  __shared__ float tile[64][65];
  const int blk = blockIdx.x;
  const int tid = threadIdx.x;
  if (blk < 8192) {
    int i = blk * 256 + tid;
    float4 v = reinterpret_cast<const float4*>(x)[i];
    ushort4 o;
    o.x = f2bf(v.x); o.y = f2bf(v.y); o.z = f2bf(v.z); o.w = f2bf(v.w);
    reinterpret_cast<ushort4*>(xb)[i] = o;
    return;
  }
  const float* W;
  unsigned short* Wt;
  int N, bx;
  if (blk < 8960) { W = W_qkv; Wt = wqkvT; N = 3072; bx = blk - 8192; }
  else            { W = W_out; Wt = woutT; N = 1024; bx = blk - 8960; }
  const int tk = (bx & 15) * 64;
  const int tn = (bx >> 4) * 64;
#pragma unroll
  for (int c = 0; c < 4; ++c) {
    int k = c * 16 + (tid >> 4);
    int n = (tid & 15) * 4;
    float4 v = *reinterpret_cast<const float4*>(&W[(size_t)(tk + k) * N + tn + n]);
    tile[k][n] = v.x; tile[k][n + 1] = v.y; tile[k][n + 2] = v.z; tile[k][n + 3] = v.w;
  }
  __syncthreads();
#pragma unroll
  for (int p = 0; p < 2; ++p) {
    int n = p * 32 + (tid >> 3);
    int k = (tid & 7) * 8;
    ushort4 a, b;
    a.x = f2bf(tile[k + 0][n]); a.y = f2bf(tile[k + 1][n]);
    a.z = f2bf(tile[k + 2][n]); a.w = f2bf(tile[k + 3][n]);
    b.x = f2bf(tile[k + 4][n]); b.y = f2bf(tile[k + 5][n]);
    b.z = f2bf(tile[k + 6][n]); b.w = f2bf(tile[k + 7][n]);
    *reinterpret_cast<ushort4*>(&Wt[(size_t)(tn + n) * 1024 + tk + k]) = a;
    *reinterpret_cast<ushort4*>(&Wt[(size_t)(tn + n) * 1024 + tk + k + 4]) = b;
  }
}

// ---------------- triple-buffered GEMM: C = A @ Bt^T + bias ----------------
// BM=256, BN=128, BK=64, 512 thr (8 waves 4Mx2N, 64x64/wave — verified fragment
// scheme). LDS 144KB: 3 buffers, 2-K-tile prefetch distance. Each iteration:
// issue 6 GLD16 into the buffer freed LAST iteration, then vmcnt(12) waits only
// for the 6 issued TWO iterations ago (~700+ cycles of compute in between —
// covers HBM latency; r5's 1-tile distance exposed ~600-cycle stalls/K-tile).
// Loads never drain in-loop (T4); 2 barriers/K-tile like the verified gemm_bt.
// xor-swizzled staging (slot = chunk ^ (row&7)), 0 bank conflicts measured.
template <int MODE>
__global__ __launch_bounds__(512, 2) void gemm8(const unsigned short* __restrict__ A,
                                                const unsigned short* __restrict__ Bt,
                                                const float* __restrict__ bias,
                                                float* __restrict__ outF,
                                                unsigned short* __restrict__ q_ws,
                                                unsigned short* __restrict__ k_ws,
                                                unsigned short* __restrict__ vt_ws,
                                                int N) {
  constexpr int K = 1024;
  __shared__ unsigned short As[3][256 * 64];  // 96KB
  __shared__ unsigned short Bs[3][128 * 64];  // 48KB
  const int tid = threadIdx.x;
  const int wave = tid >> 6, lane = tid & 63;
  const int quad = lane >> 4, l15 = lane & 15;
  const int m0 = blockIdx.x * 256, n0 = blockIdx.y * 128;
  const int wm = (wave & 3) * 64, wn = (wave >> 2) * 64;

  const f32x4 zf = {0.f, 0.f, 0.f, 0.f};
  f32x4 acc[4][4];
#pragma unroll
  for (int i = 0; i < 4; ++i)
#pragma unroll
    for (int j = 0; j < 4; ++j) acc[i][j] = zf;

  // staging: row = c*64 + (tid>>3), slot = tid&7; source chunk xor'd so readers
  // find data chunk ck of row r at slot ck^(r&7). A: 4 GLDs (256 rows), B: 2.
  const int rr = tid >> 3;
  const int scol = ((tid & 7) ^ (rr & 7)) * 8;
  const int swz = l15 & 7;
  const unsigned short* Arow = &A[(size_t)(m0 + rr) * K + scol];
  const unsigned short* Brow = &Bt[(size_t)(n0 + rr) * K + scol];

  // prologue: stage K-tiles 0,1 into bufs 0,1 (12 GLDs in flight)
#pragma unroll
  for (int tt = 0; tt < 2; ++tt) {
#pragma unroll
    for (int c = 0; c < 4; ++c)
      GLD16(Arow + (size_t)c * 64 * K + tt * 64, &As[tt][c * 4096 + tid * 8]);
#pragma unroll
    for (int c = 0; c < 2; ++c)
      GLD16(Brow + (size_t)c * 64 * K + tt * 64, &Bs[tt][c * 4096 + tid * 8]);
  }

  for (int t = 0; t < 16; ++t) {
    const int cur = t % 3, fut = (t + 2) % 3;  // fut buffer was consumed at t-1's end
    const int pf = (t + 2 < 16) ? t + 2 : 15;  // tail re-stage: harmless, never read
#pragma unroll
    for (int c = 0; c < 4; ++c)
      GLD16(Arow + (size_t)c * 64 * K + pf * 64, &As[fut][c * 4096 + tid * 8]);
#pragma unroll
    for (int c = 0; c < 2; ++c)
      GLD16(Brow + (size_t)c * 64 * K + pf * 64, &Bs[fut][c * 4096 + tid * 8]);
    // 18 outstanding -> wait to 12: exactly tile t's 6 (issued 2 iters ago) landed
    asm volatile("s_waitcnt vmcnt(12)\n\ts_barrier" ::: "memory");

#pragma unroll
    for (int kk = 0; kk < 2; ++kk) {
      const int ch = (kk * 4 + quad) ^ swz;
      short8 af[4], bg[4];
#pragma unroll
      for (int i = 0; i < 4; ++i)
        af[i] = *reinterpret_cast<const short8*>(&As[cur][(wm + i * 16 + l15) * 64 + ch * 8]);
#pragma unroll
      for (int j = 0; j < 4; ++j)
        bg[j] = *reinterpret_cast<const short8*>(&Bs[cur][(wn + j * 16 + l15) * 64 + ch * 8]);
      __builtin_amdgcn_s_setprio(1);
#pragma unroll
      for (int i = 0; i < 4; ++i)
#pragma unroll
        for (int j = 0; j < 4; ++j) acc[i][j] = MFMA_BF16(af[i], bg[j], acc[i][j]);
      __builtin_amdgcn_s_setprio(0);
    }
    // all waves done reading buf[cur]; next iteration stages into it
    asm volatile("s_barrier" ::: "memory");
  }
  // drain prefetch before exit (outstanding GLD would corrupt successor's LDS)
  asm volatile("s_waitcnt vmcnt(0)" ::: "memory");

  const float kScQ = 0.125f * 1.44269504088896f;  // log2(e)/sqrt(64)
  const int cls = n0 >> 10;
#pragma unroll
  for (int i = 0; i < 4; ++i) {
#pragma unroll
    for (int j = 0; j < 4; ++j) {
      const int n = n0 + wn + j * 16 + l15;
      const float bv = bias[n];
      const int mb = m0 + wm + i * 16 + quad * 4;
      if (MODE == 1) {
#pragma unroll
        for (int r = 0; r < 4; ++r) outF[(size_t)(mb + r) * N + n] = acc[i][j][r] + bv;
      } else if (cls == 0) {
        const int b = mb >> 11, t0 = mb & 2047;
        const int h = n >> 6, d = n & 63;
#pragma unroll
        for (int r = 0; r < 4; ++r)
          q_ws[(((size_t)(b * 16 + h)) * 2048 + t0 + r) * 64 + d] =
              f2bf((acc[i][j][r] + bv) * kScQ);
      } else if (cls == 1) {
        const int b = mb >> 11, t0 = mb & 2047;
        const int n2 = n - 1024, h = n2 >> 6, d = n2 & 63;
#pragma unroll
        for (int r = 0; r < 4; ++r)
          k_ws[(((size_t)(b * 16 + h)) * 2048 + t0 + r) * 64 + d] = f2bf(acc[i][j][r] + bv);
      } else {
        const int b = mb >> 11, t0 = mb & 2047;
        const int n2 = n - 2048, h = n2 >> 6, d = n2 & 63;
        uint2 pk;
        pk.x = __builtin_bit_cast(unsigned int,
                                  __builtin_amdgcn_cvt_pkrtz(acc[i][j][0] + bv, acc[i][j][1] + bv));
        pk.y = __builtin_bit_cast(unsigned int,
                                  __builtin_amdgcn_cvt_pkrtz(acc[i][j][2] + bv, acc[i][j][3] + bv));
        *reinterpret_cast<uint2*>(
            &vt_ws[(((size_t)(b * 16 + h)) * 64 + d) * 2048 + t0]) = pk;
      }
    }
  }
}

// ---------------- flash attention: 32x32 MFMA, 4 waves, split softmax/PV pipeline ----
// (r3 structure — best measured variant at ~69us.)
// Q,K: [B*H, T, 64] bf16 (Q pre-scaled, log2 domain); Vt: [B*H, 64, T] fp16.
__global__ __launch_bounds__(256, 3) void attn_k(const unsigned short* __restrict__ q_ws,
                                                 const unsigned short* __restrict__ k_ws,
                                                 const unsigned short* __restrict__ vt_ws,
                                                 unsigned short* __restrict__ att_ws) {
  const int T = 2048;
  const int bid = blockIdx.x;
  const int bh = (bid & 7) * 8 + ((bid >> 3) & 7);  // XCD-locality swizzle
  const int s = 15 - (bid >> 6);                    // heaviest strips first (LPT)
  const int tid = threadIdx.x;
  const int wv = tid >> 6, lane = tid & 63;
  const int L = lane & 31, hl = lane >> 5;

  const unsigned short* Qh = q_ws + (size_t)bh * T * 64;
  const unsigned short* Kh = k_ws + (size_t)bh * T * 64;
  const _Float16* Vh = (const _Float16*)vt_ws + (size_t)bh * 64 * T;
  const int b = bh >> 4, h = bh & 15;

  __shared__ unsigned short Ks[2][64 * 64];  // dbuf, xor-swizzled 8-elem chunks
  __shared__ _Float16 Vs[2][64 * 64];

  const int qw = s * 4 + wv;     // 32-query tile index 0..63
  const int q0 = qw * 32;
  const int diagTile = qw >> 1;  // last 64-key tile this wave needs
  const int nk = 2 * s + 2;      // block-uniform trip count
  const int myq = q0 + L;

  short8 qb[4];
#pragma unroll
  for (int kk = 0; kk < 4; ++kk)
    qb[kk] = *reinterpret_cast<const short8*>(&Qh[(size_t)(q0 + L) * 64 + kk * 16 + hl * 8]);

  f32x16 o0 = {}, o1 = {};
  float2v li = {0.f, 0.f};

  const int srow8 = tid >> 3;
  const int schunk = (tid & 7) ^ (srow8 & 7);

  GLD16(&Kh[(size_t)srow8 * 64 + schunk * 8], &Ks[0][tid * 8]);
  GLD16(&Kh[(size_t)(32 + srow8) * 64 + schunk * 8], &Ks[0][2048 + tid * 8]);
  GLD16(&Vh[(size_t)srow8 * T + schunk * 8], &Vs[0][tid * 8]);
  GLD16(&Vh[(size_t)(32 + srow8) * T + schunk * 8], &Vs[0][2048 + tid * 8]);

  auto softmax32 = [&](const f32x16& scc, unsigned (&pwc)[4][2]) {
#pragma unroll
    for (int g = 0; g < 4; ++g) {
      float2v e01, e23;
      e01[0] = __builtin_amdgcn_exp2f(scc[4 * g + 0]);
      e01[1] = __builtin_amdgcn_exp2f(scc[4 * g + 1]);
      e23[0] = __builtin_amdgcn_exp2f(scc[4 * g + 2]);
      e23[1] = __builtin_amdgcn_exp2f(scc[4 * g + 3]);
      float2v s2;
      asm("v_pk_add_f32 %0, %1, %2" : "=v"(s2) : "v"(e01), "v"(e23));
      asm("v_pk_add_f32 %0, %0, %1" : "+v"(li) : "v"(s2));
      pwc[g][0] = __builtin_bit_cast(unsigned int, __builtin_amdgcn_cvt_pkrtz(e01[0], e01[1]));
      pwc[g][1] = __builtin_bit_cast(unsigned int, __builtin_amdgcn_cvt_pkrtz(e23[0], e23[1]));
    }
#pragma unroll
    for (int r = 0; r < 2; ++r) {
      asm volatile("v_permlane32_swap_b32 %0, %1" : "+v"(pwc[0][r]), "+v"(pwc[1][r]));
      asm volatile("v_permlane32_swap_b32 %0, %1" : "+v"(pwc[2][r]), "+v"(pwc[3][r]));
    }
  };

  for (int kt = 0; kt < nk; ++kt) {
    const int cur = kt & 1, nxt = cur ^ 1;
    if (kt) asm volatile("s_barrier" ::: "memory");  // all waves done with buf[nxt]
    const int pf = (kt + 1 < nk) ? kt + 1 : nk - 1;
    GLD16(&Kh[(size_t)(pf * 64 + srow8) * 64 + schunk * 8], &Ks[nxt][tid * 8]);
    GLD16(&Kh[(size_t)(pf * 64 + 32 + srow8) * 64 + schunk * 8], &Ks[nxt][2048 + tid * 8]);
    GLD16(&Vh[(size_t)srow8 * T + pf * 64 + schunk * 8], &Vs[nxt][tid * 8]);
    GLD16(&Vh[(size_t)(32 + srow8) * T + pf * 64 + schunk * 8], &Vs[nxt][2048 + tid * 8]);
    asm volatile("s_waitcnt vmcnt(4)\n\ts_barrier" ::: "memory");

    if (kt <= diagTile) {
      const unsigned short* KsC = Ks[cur];
      const _Float16* VsC = Vs[cur];
      const int kb = kt * 64;

      f32x16 sc0 = {}, sc1 = {};
      __builtin_amdgcn_s_setprio(1);
#pragma unroll
      for (int kk = 0; kk < 4; ++kk) {
        const int sl = ((kk * 2 + hl) ^ (L & 7)) * 8;
        short8 k0 = *reinterpret_cast<const short8*>(&KsC[L * 64 + sl]);
        short8 k1 = *reinterpret_cast<const short8*>(&KsC[(32 + L) * 64 + sl]);
        sc0 = MFMA32_BF16(k0, qb[kk], sc0);
        sc1 = MFMA32_BF16(k1, qb[kk], sc1);
      }
      __builtin_amdgcn_s_setprio(0);

      half8 vr0[2], vr1[2];
#pragma unroll
      for (int t = 0; t < 2; ++t) {
        const int sl = ((t * 2 + hl) ^ (L & 7)) * 8;
        vr0[t] = *reinterpret_cast<const half8*>(&VsC[L * 64 + sl]);
        vr1[t] = *reinterpret_cast<const half8*>(&VsC[(32 + L) * 64 + sl]);
      }

      if (kt == diagTile) {
#pragma unroll
        for (int reg = 0; reg < 16; ++reg) {
          const int row = (reg & 3) + 8 * (reg >> 2) + 4 * hl;
          sc0[reg] = (kb + row > myq) ? -1e30f : sc0[reg];
        }
      }
      unsigned pw0[4][2], pw1[4][2];
      softmax32(sc0, pw0);

      half8 vr2[2], vr3[2];
#pragma unroll
      for (int t = 2; t < 4; ++t) {
        const int sl = ((t * 2 + hl) ^ (L & 7)) * 8;
        vr2[t - 2] = *reinterpret_cast<const half8*>(&VsC[L * 64 + sl]);
        vr3[t - 2] = *reinterpret_cast<const half8*>(&VsC[(32 + L) * 64 + sl]);
      }

      __builtin_amdgcn_s_setprio(1);
      {
        uint4v f0 = {pw0[0][0], pw0[0][1], pw0[1][0], pw0[1][1]};
        uint4v f1 = {pw0[2][0], pw0[2][1], pw0[3][0], pw0[3][1]};
        half8 pb0 = __builtin_bit_cast(half8, f0);
        half8 pb1 = __builtin_bit_cast(half8, f1);
        o0 = MFMA32_F16(vr0[0], pb0, o0);
        o1 = MFMA32_F16(vr1[0], pb0, o1);
        o0 = MFMA32_F16(vr0[1], pb1, o0);
        o1 = MFMA32_F16(vr1[1], pb1, o1);
      }
      __builtin_amdgcn_s_setprio(0);

      if (kt == diagTile) {
#pragma unroll
        for (int reg = 0; reg < 16; ++reg) {
          const int row = (reg & 3) + 8 * (reg >> 2) + 4 * hl;
          sc1[reg] = (kb + 32 + row > myq) ? -1e30f : sc1[reg];
        }
      }
      softmax32(sc1, pw1);

      __builtin_amdgcn_s_setprio(1);
      {
        uint4v f0 = {pw1[0][0], pw1[0][1], pw1[1][0], pw1[1][1]};
        uint4v f1 = {pw1[2][0], pw1[2][1], pw1[3][0], pw1[3][1]};
        half8 pb0 = __builtin_bit_cast(half8, f0);
        half8 pb1 = __builtin_bit_cast(half8, f1);
        o0 = MFMA32_F16(vr2[0], pb0, o0);
        o1 = MFMA32_F16(vr3[0], pb0, o1);
        o0 = MFMA32_F16(vr2[1], pb1, o0);
        o1 = MFMA32_F16(vr3[1], pb1, o1);
      }
      __builtin_amdgcn_s_setprio(0);
    }
  }
  asm volatile("s_waitcnt vmcnt(0)" ::: "memory");

  float l_i = li[0] + li[1];
  l_i += __shfl_xor(l_i, 32);
  const float inv = 1.f / l_i;
#pragma unroll
  for (int sg = 0; sg < 2; ++sg) {
    const f32x16& oo = sg ? o1 : o0;
#pragma unroll
    for (int g = 0; g < 4; ++g) {
      const int d0 = sg * 32 + g * 8 + hl * 4;
      uint2 ov;
      ov.x = (unsigned)f2bf(oo[4 * g + 0] * inv) | ((unsigned)f2bf(oo[4 * g + 1] * inv) << 16);
      ov.y = (unsigned)f2bf(oo[4 * g + 2] * inv) | ((unsigned)f2bf(oo[4 * g + 3] * inv) << 16);
      *reinterpret_cast<uint2*>(
          &att_ws[(size_t)(b * 2048 + q0 + L) * 1024 + h * 64 + d0]) = ov;
    }
  }
}

// ---------------- launch ----------------
extern "C" void kernel_launch(void* const* d_in, const int* in_sizes, int n_in,
                              void* d_out, int out_size, void* d_ws, size_t ws_size,
                              hipStream_t stream) {
  (void)in_sizes; (void)n_in; (void)out_size; (void)ws_size;
  const float* x     = (const float*)d_in[0];
  const float* W_qkv = (const float*)d_in[1];
  const float* b_qkv = (const float*)d_in[2];
  const float* W_out = (const float*)d_in[3];
  const float* b_out = (const float*)d_in[4];
  float* out = (float*)d_out;

  char* ws = (char*)d_ws;
  unsigned short* xb    = (unsigned short*)(ws);
  unsigned short* wqkvT = (unsigned short*)(ws + 16777216);
  unsigned short* woutT = (unsigned short*)(ws + 23068672);
  unsigned short* q_ws  = (unsigned short*)(ws + 25165824);
  unsigned short* k_ws  = (unsigned short*)(ws + 41943040);
  unsigned short* vt_ws = (unsigned short*)(ws + 58720256);
  unsigned short* attb  = (unsigned short*)(ws + 75497472);

  prep_k<<<9216, 256, 0, stream>>>(x, xb, W_qkv, wqkvT, W_out, woutT);

  dim3 g1(32, 24);  // 768 blocks @ 1/CU = 3 clean rounds
  gemm8<0><<<g1, 512, 0, stream>>>(xb, wqkvT, b_qkv, nullptr, q_ws, k_ws, vt_ws, 3072);

  attn_k<<<1024, 256, 0, stream>>>(q_ws, k_ws, vt_ws, attb);

  dim3 g2(32, 8);   // 256 blocks = exactly 1 round
  gemm8<1><<<g2, 512, 0, stream>>>(attb, woutT, b_out, out, nullptr, nullptr, nullptr, 1024);
}

// Round 8
// 230.729 us; speedup vs baseline: 1.3834x; 1.0626x over previous
//
#include <hip/hip_runtime.h>

typedef __attribute__((ext_vector_type(8))) short short8;    // bf16 frag
typedef __attribute__((ext_vector_type(8))) _Float16 half8;  // f16 frag
typedef __attribute__((ext_vector_type(4))) float f32x4;
typedef __attribute__((ext_vector_type(16))) float f32x16;
typedef __attribute__((ext_vector_type(4))) unsigned uint4v;
typedef __attribute__((ext_vector_type(2))) float float2v;

#define MFMA_BF16(a, b, c) __builtin_amdgcn_mfma_f32_16x16x32_bf16(a, b, c, 0, 0, 0)
#define MFMA32_BF16(a, b, c) __builtin_amdgcn_mfma_f32_32x32x16_bf16(a, b, c, 0, 0, 0)
#define MFMA32_F16(a, b, c) __builtin_amdgcn_mfma_f32_32x32x16_f16(a, b, c, 0, 0, 0)

#define GLD16(g, l)                                                          \
  __builtin_amdgcn_global_load_lds(                                          \
      (const __attribute__((address_space(1))) unsigned int*)(g),            \
      (__attribute__((address_space(3))) unsigned int*)(l), 16, 0, 0)

__device__ __forceinline__ unsigned short f2bf(float f) {
  unsigned int u = __float_as_uint(f);
  u += 0x7fffu + ((u >> 16) & 1u);
  return (unsigned short)(u >> 16);
}

// ---------------- merged prep: x->bf16 cvt + two weight transposes ----------------
__global__ __launch_bounds__(256) void prep_k(const float* __restrict__ x,
                                              unsigned short* __restrict__ xb,
                                              const float* __restrict__ W_qkv,
                                              unsigned short* __restrict__ wqkvT,
                                              const float* __restrict__ W_out,
                                              unsigned short* __restrict__ woutT) {
  __shared__ float tile[64][65];
  const int blk = blockIdx.x;
  const int tid = threadIdx.x;
  if (blk < 8192) {
    int i = blk * 256 + tid;
    float4 v = reinterpret_cast<const float4*>(x)[i];
    ushort4 o;
    o.x = f2bf(v.x); o.y = f2bf(v.y); o.z = f2bf(v.z); o.w = f2bf(v.w);
    reinterpret_cast<ushort4*>(xb)[i] = o;
    return;
  }
  const float* W;
  unsigned short* Wt;
  int N, bx;
  if (blk < 8960) { W = W_qkv; Wt = wqkvT; N = 3072; bx = blk - 8192; }
  else            { W = W_out; Wt = woutT; N = 1024; bx = blk - 8960; }
  const int tk = (bx & 15) * 64;
  const int tn = (bx >> 4) * 64;
#pragma unroll
  for (int c = 0; c < 4; ++c) {
    int k = c * 16 + (tid >> 4);
    int n = (tid & 15) * 4;
    float4 v = *reinterpret_cast<const float4*>(&W[(size_t)(tk + k) * N + tn + n]);
    tile[k][n] = v.x; tile[k][n + 1] = v.y; tile[k][n + 2] = v.z; tile[k][n + 3] = v.w;
  }
  __syncthreads();
#pragma unroll
  for (int p = 0; p < 2; ++p) {
    int n = p * 32 + (tid >> 3);
    int k = (tid & 7) * 8;
    ushort4 a, b;
    a.x = f2bf(tile[k + 0][n]); a.y = f2bf(tile[k + 1][n]);
    a.z = f2bf(tile[k + 2][n]); a.w = f2bf(tile[k + 3][n]);
    b.x = f2bf(tile[k + 4][n]); b.y = f2bf(tile[k + 5][n]);
    b.z = f2bf(tile[k + 6][n]); b.w = f2bf(tile[k + 7][n]);
    *reinterpret_cast<ushort4*>(&Wt[(size_t)(tn + n) * 1024 + tk + k]) = a;
    *reinterpret_cast<ushort4*>(&Wt[(size_t)(tn + n) * 1024 + tk + k + 4]) = b;
  }
}

// ---------------- GEMM A: 4-wave 128xBN (proven ~70us on QKV) ----------
// xor-swizzled LDS (slot = chunk ^ (row&7)); multi-block TLP beats single-block
// lockstep schedules here (r5/r6 A/B).
template <int MODE, int BN>
__global__ __launch_bounds__(256) void gemm_bt(const unsigned short* __restrict__ A,
                                               const unsigned short* __restrict__ Bt,
                                               const float* __restrict__ bias,
                                               float* __restrict__ outF,
                                               unsigned short* __restrict__ q_ws,
                                               unsigned short* __restrict__ k_ws,
                                               unsigned short* __restrict__ vt_ws,
                                               int M, int N, int K) {
  constexpr int NJ = BN / 32;
  constexpr int NBC = BN * 64 / 2048;
  __shared__ unsigned short As[128 * 64];
  __shared__ unsigned short Bs[BN * 64];

  const int tid = threadIdx.x;
  const int wave = tid >> 6, lane = tid & 63;
  const int quad = lane >> 4, l15 = lane & 15;
  const int m0 = blockIdx.x * 128, n0 = blockIdx.y * BN;
  const int wm = (wave & 1) * 64, wn = (wave >> 1) * (BN / 2);

  const f32x4 zf = {0.f, 0.f, 0.f, 0.f};
  f32x4 acc[4][NJ];
#pragma unroll
  for (int i = 0; i < 4; ++i)
#pragma unroll
    for (int j = 0; j < NJ; ++j) acc[i][j] = zf;

  const int rr = tid >> 3;
  const int scol = ((tid & 7) ^ (rr & 7)) * 8;
  const int swz = l15 & 7;

  for (int kt = 0; kt < K; kt += 64) {
    __syncthreads();
#pragma unroll
    for (int c = 0; c < 4; ++c)
      GLD16(&A[(size_t)(m0 + c * 32 + rr) * K + kt + scol], &As[c * 2048 + tid * 8]);
#pragma unroll
    for (int c = 0; c < NBC; ++c)
      GLD16(&Bt[(size_t)(n0 + c * 32 + rr) * K + kt + scol], &Bs[c * 2048 + tid * 8]);
    __syncthreads();

#pragma unroll
    for (int kk = 0; kk < 2; ++kk) {
      const int ch = (kk * 4 + quad) ^ swz;
      short8 af[4], bg[NJ];
#pragma unroll
      for (int i = 0; i < 4; ++i)
        af[i] = *reinterpret_cast<const short8*>(&As[(wm + i * 16 + l15) * 64 + ch * 8]);
#pragma unroll
      for (int j = 0; j < NJ; ++j)
        bg[j] = *reinterpret_cast<const short8*>(&Bs[(wn + j * 16 + l15) * 64 + ch * 8]);
#pragma unroll
      for (int i = 0; i < 4; ++i)
#pragma unroll
        for (int j = 0; j < NJ; ++j) acc[i][j] = MFMA_BF16(af[i], bg[j], acc[i][j]);
    }
  }

  const float kScQ = 0.125f * 1.44269504088896f;  // log2(e)/sqrt(64)
  const int cls = n0 >> 10;
#pragma unroll
  for (int i = 0; i < 4; ++i) {
#pragma unroll
    for (int j = 0; j < NJ; ++j) {
      const int n = n0 + wn + j * 16 + l15;
      const float bv = bias[n];
      const int mb = m0 + wm + i * 16 + quad * 4;
      if (MODE == 1) {
#pragma unroll
        for (int r = 0; r < 4; ++r) outF[(size_t)(mb + r) * N + n] = acc[i][j][r] + bv;
      } else if (cls == 0) {
        const int b = mb >> 11, t0 = mb & 2047;
        const int h = n >> 6, d = n & 63;
#pragma unroll
        for (int r = 0; r < 4; ++r)
          q_ws[(((size_t)(b * 16 + h)) * 2048 + t0 + r) * 64 + d] =
              f2bf((acc[i][j][r] + bv) * kScQ);
      } else if (cls == 1) {
        const int b = mb >> 11, t0 = mb & 2047;
        const int n2 = n - 1024, h = n2 >> 6, d = n2 & 63;
#pragma unroll
        for (int r = 0; r < 4; ++r)
          k_ws[(((size_t)(b * 16 + h)) * 2048 + t0 + r) * 64 + d] = f2bf(acc[i][j][r] + bv);
      } else {
        const int b = mb >> 11, t0 = mb & 2047;
        const int n2 = n - 2048, h = n2 >> 6, d = n2 & 63;
        uint2 pk;
        pk.x = __builtin_bit_cast(unsigned int,
                                  __builtin_amdgcn_cvt_pkrtz(acc[i][j][0] + bv, acc[i][j][1] + bv));
        pk.y = __builtin_bit_cast(unsigned int,
                                  __builtin_amdgcn_cvt_pkrtz(acc[i][j][2] + bv, acc[i][j][3] + bv));
        *reinterpret_cast<uint2*>(
            &vt_ws[(((size_t)(b * 16 + h)) * 64 + d) * 2048 + t0]) = pk;
      }
    }
  }
}

// ---------------- GEMM B: 8-wave 256x128, triple-buffered (used for PROJ) ----------
// Per-wave 64x64 = 16 MFMA per 8 ds_reads per kk — 3x fewer LDS reads per output
// than gemm_bt<BN=64>. Worse than gemm_bt on the big QKV GEMM (lockstep, r5/r6)
// but the right shape for the small proj GEMM (256 blocks, LDS-read-light).
template <int MODE>
__global__ __launch_bounds__(512, 2) void gemm8(const unsigned short* __restrict__ A,
                                                const unsigned short* __restrict__ Bt,
                                                const float* __restrict__ bias,
                                                float* __restrict__ outF,
                                                unsigned short* __restrict__ q_ws,
                                                unsigned short* __restrict__ k_ws,
                                                unsigned short* __restrict__ vt_ws,
                                                int N) {
  constexpr int K = 1024;
  __shared__ unsigned short As[3][256 * 64];  // 96KB
  __shared__ unsigned short Bs[3][128 * 64];  // 48KB
  const int tid = threadIdx.x;
  const int wave = tid >> 6, lane = tid & 63;
  const int quad = lane >> 4, l15 = lane & 15;
  const int m0 = blockIdx.x * 256, n0 = blockIdx.y * 128;
  const int wm = (wave & 3) * 64, wn = (wave >> 2) * 64;

  const f32x4 zf = {0.f, 0.f, 0.f, 0.f};
  f32x4 acc[4][4];
#pragma unroll
  for (int i = 0; i < 4; ++i)
#pragma unroll
    for (int j = 0; j < 4; ++j) acc[i][j] = zf;

  const int rr = tid >> 3;
  const int scol = ((tid & 7) ^ (rr & 7)) * 8;
  const int swz = l15 & 7;
  const unsigned short* Arow = &A[(size_t)(m0 + rr) * K + scol];
  const unsigned short* Brow = &Bt[(size_t)(n0 + rr) * K + scol];

#pragma unroll
  for (int tt = 0; tt < 2; ++tt) {
#pragma unroll
    for (int c = 0; c < 4; ++c)
      GLD16(Arow + (size_t)c * 64 * K + tt * 64, &As[tt][c * 4096 + tid * 8]);
#pragma unroll
    for (int c = 0; c < 2; ++c)
      GLD16(Brow + (size_t)c * 64 * K + tt * 64, &Bs[tt][c * 4096 + tid * 8]);
  }

  for (int t = 0; t < 16; ++t) {
    const int cur = t % 3, fut = (t + 2) % 3;
    const int pf = (t + 2 < 16) ? t + 2 : 15;  // tail re-stage: harmless, never read
#pragma unroll
    for (int c = 0; c < 4; ++c)
      GLD16(Arow + (size_t)c * 64 * K + pf * 64, &As[fut][c * 4096 + tid * 8]);
#pragma unroll
    for (int c = 0; c < 2; ++c)
      GLD16(Brow + (size_t)c * 64 * K + pf * 64, &Bs[fut][c * 4096 + tid * 8]);
    asm volatile("s_waitcnt vmcnt(12)\n\ts_barrier" ::: "memory");

#pragma unroll
    for (int kk = 0; kk < 2; ++kk) {
      const int ch = (kk * 4 + quad) ^ swz;
      short8 af[4], bg[4];
#pragma unroll
      for (int i = 0; i < 4; ++i)
        af[i] = *reinterpret_cast<const short8*>(&As[cur][(wm + i * 16 + l15) * 64 + ch * 8]);
#pragma unroll
      for (int j = 0; j < 4; ++j)
        bg[j] = *reinterpret_cast<const short8*>(&Bs[cur][(wn + j * 16 + l15) * 64 + ch * 8]);
      __builtin_amdgcn_s_setprio(1);
#pragma unroll
      for (int i = 0; i < 4; ++i)
#pragma unroll
        for (int j = 0; j < 4; ++j) acc[i][j] = MFMA_BF16(af[i], bg[j], acc[i][j]);
      __builtin_amdgcn_s_setprio(0);
    }
    asm volatile("s_barrier" ::: "memory");
  }
  asm volatile("s_waitcnt vmcnt(0)" ::: "memory");

  const float kScQ = 0.125f * 1.44269504088896f;
  const int cls = n0 >> 10;
#pragma unroll
  for (int i = 0; i < 4; ++i) {
#pragma unroll
    for (int j = 0; j < 4; ++j) {
      const int n = n0 + wn + j * 16 + l15;
      const float bv = bias[n];
      const int mb = m0 + wm + i * 16 + quad * 4;
      if (MODE == 1) {
#pragma unroll
        for (int r = 0; r < 4; ++r) outF[(size_t)(mb + r) * N + n] = acc[i][j][r] + bv;
      } else if (cls == 0) {
        const int b = mb >> 11, t0 = mb & 2047;
        const int h = n >> 6, d = n & 63;
#pragma unroll
        for (int r = 0; r < 4; ++r)
          q_ws[(((size_t)(b * 16 + h)) * 2048 + t0 + r) * 64 + d] =
              f2bf((acc[i][j][r] + bv) * kScQ);
      } else if (cls == 1) {
        const int b = mb >> 11, t0 = mb & 2047;
        const int n2 = n - 1024, h = n2 >> 6, d = n2 & 63;
#pragma unroll
        for (int r = 0; r < 4; ++r)
          k_ws[(((size_t)(b * 16 + h)) * 2048 + t0 + r) * 64 + d] = f2bf(acc[i][j][r] + bv);
      } else {
        const int b = mb >> 11, t0 = mb & 2047;
        const int n2 = n - 2048, h = n2 >> 6, d = n2 & 63;
        uint2 pk;
        pk.x = __builtin_bit_cast(unsigned int,
                                  __builtin_amdgcn_cvt_pkrtz(acc[i][j][0] + bv, acc[i][j][1] + bv));
        pk.y = __builtin_bit_cast(unsigned int,
                                  __builtin_amdgcn_cvt_pkrtz(acc[i][j][2] + bv, acc[i][j][3] + bv));
        *reinterpret_cast<uint2*>(
            &vt_ws[(((size_t)(b * 16 + h)) * 64 + d) * 2048 + t0]) = pk;
      }
    }
  }
}

// ---------------- flash attention: 32x32 MFMA, 4 waves, split softmax/PV pipeline ----
// EXACT r3/r6 configuration (passed 7x at ~69us). NOTE: __launch_bounds__(256,4)
// (r7) caused a NONDETERMINISTIC correctness failure — do not raise min-waves on
// this kernel without re-verifying the dbuf barrier protocol under that regime.
__global__ __launch_bounds__(256, 3) void attn_k(const unsigned short* __restrict__ q_ws,
                                                 const unsigned short* __restrict__ k_ws,
                                                 const unsigned short* __restrict__ vt_ws,
                                                 unsigned short* __restrict__ att_ws) {
  const int T = 2048;
  const int bid = blockIdx.x;
  const int bh = (bid & 7) * 8 + ((bid >> 3) & 7);  // XCD-locality swizzle
  const int s = 15 - (bid >> 6);                    // heaviest strips first (LPT)
  const int tid = threadIdx.x;
  const int wv = tid >> 6, lane = tid & 63;
  const int L = lane & 31, hl = lane >> 5;

  const unsigned short* Qh = q_ws + (size_t)bh * T * 64;
  const unsigned short* Kh = k_ws + (size_t)bh * T * 64;
  const _Float16* Vh = (const _Float16*)vt_ws + (size_t)bh * 64 * T;
  const int b = bh >> 4, h = bh & 15;

  __shared__ unsigned short Ks[2][64 * 64];  // dbuf, xor-swizzled 8-elem chunks
  __shared__ _Float16 Vs[2][64 * 64];

  const int qw = s * 4 + wv;     // 32-query tile index 0..63
  const int q0 = qw * 32;
  const int diagTile = qw >> 1;  // last 64-key tile this wave needs
  const int nk = 2 * s + 2;      // block-uniform trip count
  const int myq = q0 + L;

  short8 qb[4];
#pragma unroll
  for (int kk = 0; kk < 4; ++kk)
    qb[kk] = *reinterpret_cast<const short8*>(&Qh[(size_t)(q0 + L) * 64 + kk * 16 + hl * 8]);

  f32x16 o0 = {}, o1 = {};
  float2v li = {0.f, 0.f};

  const int srow8 = tid >> 3;
  const int schunk = (tid & 7) ^ (srow8 & 7);

  GLD16(&Kh[(size_t)srow8 * 64 + schunk * 8], &Ks[0][tid * 8]);
  GLD16(&Kh[(size_t)(32 + srow8) * 64 + schunk * 8], &Ks[0][2048 + tid * 8]);
  GLD16(&Vh[(size_t)srow8 * T + schunk * 8], &Vs[0][tid * 8]);
  GLD16(&Vh[(size_t)(32 + srow8) * T + schunk * 8], &Vs[0][2048 + tid * 8]);

  auto softmax32 = [&](const f32x16& scc, unsigned (&pwc)[4][2]) {
#pragma unroll
    for (int g = 0; g < 4; ++g) {
      float2v e01, e23;
      e01[0] = __builtin_amdgcn_exp2f(scc[4 * g + 0]);
      e01[1] = __builtin_amdgcn_exp2f(scc[4 * g + 1]);
      e23[0] = __builtin_amdgcn_exp2f(scc[4 * g + 2]);
      e23[1] = __builtin_amdgcn_exp2f(scc[4 * g + 3]);
      float2v s2;
      asm("v_pk_add_f32 %0, %1, %2" : "=v"(s2) : "v"(e01), "v"(e23));
      asm("v_pk_add_f32 %0, %0, %1" : "+v"(li) : "v"(s2));
      pwc[g][0] = __builtin_bit_cast(unsigned int, __builtin_amdgcn_cvt_pkrtz(e01[0], e01[1]));
      pwc[g][1] = __builtin_bit_cast(unsigned int, __builtin_amdgcn_cvt_pkrtz(e23[0], e23[1]));
    }
#pragma unroll
    for (int r = 0; r < 2; ++r) {
      asm volatile("v_permlane32_swap_b32 %0, %1" : "+v"(pwc[0][r]), "+v"(pwc[1][r]));
      asm volatile("v_permlane32_swap_b32 %0, %1" : "+v"(pwc[2][r]), "+v"(pwc[3][r]));
    }
  };

  for (int kt = 0; kt < nk; ++kt) {
    const int cur = kt & 1, nxt = cur ^ 1;
    if (kt) asm volatile("s_barrier" ::: "memory");  // all waves done with buf[nxt]
    const int pf = (kt + 1 < nk) ? kt + 1 : nk - 1;
    GLD16(&Kh[(size_t)(pf * 64 + srow8) * 64 + schunk * 8], &Ks[nxt][tid * 8]);
    GLD16(&Kh[(size_t)(pf * 64 + 32 + srow8) * 64 + schunk * 8], &Ks[nxt][2048 + tid * 8]);
    GLD16(&Vh[(size_t)srow8 * T + pf * 64 + schunk * 8], &Vs[nxt][tid * 8]);
    GLD16(&Vh[(size_t)(32 + srow8) * T + pf * 64 + schunk * 8], &Vs[nxt][2048 + tid * 8]);
    asm volatile("s_waitcnt vmcnt(4)\n\ts_barrier" ::: "memory");

    if (kt <= diagTile) {
      const unsigned short* KsC = Ks[cur];
      const _Float16* VsC = Vs[cur];
      const int kb = kt * 64;

      f32x16 sc0 = {}, sc1 = {};
      __builtin_amdgcn_s_setprio(1);
#pragma unroll
      for (int kk = 0; kk < 4; ++kk) {
        const int sl = ((kk * 2 + hl) ^ (L & 7)) * 8;
        short8 k0 = *reinterpret_cast<const short8*>(&KsC[L * 64 + sl]);
        short8 k1 = *reinterpret_cast<const short8*>(&KsC[(32 + L) * 64 + sl]);
        sc0 = MFMA32_BF16(k0, qb[kk], sc0);
        sc1 = MFMA32_BF16(k1, qb[kk], sc1);
      }
      __builtin_amdgcn_s_setprio(0);

      half8 vr0[2], vr1[2];
#pragma unroll
      for (int t = 0; t < 2; ++t) {
        const int sl = ((t * 2 + hl) ^ (L & 7)) * 8;
        vr0[t] = *reinterpret_cast<const half8*>(&VsC[L * 64 + sl]);
        vr1[t] = *reinterpret_cast<const half8*>(&VsC[(32 + L) * 64 + sl]);
      }

      if (kt == diagTile) {
#pragma unroll
        for (int reg = 0; reg < 16; ++reg) {
          const int row = (reg & 3) + 8 * (reg >> 2) + 4 * hl;
          sc0[reg] = (kb + row > myq) ? -1e30f : sc0[reg];
        }
      }
      unsigned pw0[4][2], pw1[4][2];
      softmax32(sc0, pw0);

      half8 vr2[2], vr3[2];
#pragma unroll
      for (int t = 2; t < 4; ++t) {
        const int sl = ((t * 2 + hl) ^ (L & 7)) * 8;
        vr2[t - 2] = *reinterpret_cast<const half8*>(&VsC[L * 64 + sl]);
        vr3[t - 2] = *reinterpret_cast<const half8*>(&VsC[(32 + L) * 64 + sl]);
      }

      __builtin_amdgcn_s_setprio(1);
      {
        uint4v f0 = {pw0[0][0], pw0[0][1], pw0[1][0], pw0[1][1]};
        uint4v f1 = {pw0[2][0], pw0[2][1], pw0[3][0], pw0[3][1]};
        half8 pb0 = __builtin_bit_cast(half8, f0);
        half8 pb1 = __builtin_bit_cast(half8, f1);
        o0 = MFMA32_F16(vr0[0], pb0, o0);
        o1 = MFMA32_F16(vr1[0], pb0, o1);
        o0 = MFMA32_F16(vr0[1], pb1, o0);
        o1 = MFMA32_F16(vr1[1], pb1, o1);
      }
      __builtin_amdgcn_s_setprio(0);

      if (kt == diagTile) {
#pragma unroll
        for (int reg = 0; reg < 16; ++reg) {
          const int row = (reg & 3) + 8 * (reg >> 2) + 4 * hl;
          sc1[reg] = (kb + 32 + row > myq) ? -1e30f : sc1[reg];
        }
      }
      softmax32(sc1, pw1);

      __builtin_amdgcn_s_setprio(1);
      {
        uint4v f0 = {pw1[0][0], pw1[0][1], pw1[1][0], pw1[1][1]};
        uint4v f1 = {pw1[2][0], pw1[2][1], pw1[3][0], pw1[3][1]};
        half8 pb0 = __builtin_bit_cast(half8, f0);
        half8 pb1 = __builtin_bit_cast(half8, f1);
        o0 = MFMA32_F16(vr2[0], pb0, o0);
        o1 = MFMA32_F16(vr3[0], pb0, o1);
        o0 = MFMA32_F16(vr2[1], pb1, o0);
        o1 = MFMA32_F16(vr3[1], pb1, o1);
      }
      __builtin_amdgcn_s_setprio(0);
    }
  }
  asm volatile("s_waitcnt vmcnt(0)" ::: "memory");

  float l_i = li[0] + li[1];
  l_i += __shfl_xor(l_i, 32);
  const float inv = 1.f / l_i;
#pragma unroll
  for (int sg = 0; sg < 2; ++sg) {
    const f32x16& oo = sg ? o1 : o0;
#pragma unroll
    for (int g = 0; g < 4; ++g) {
      const int d0 = sg * 32 + g * 8 + hl * 4;
      uint2 ov;
      ov.x = (unsigned)f2bf(oo[4 * g + 0] * inv) | ((unsigned)f2bf(oo[4 * g + 1] * inv) << 16);
      ov.y = (unsigned)f2bf(oo[4 * g + 2] * inv) | ((unsigned)f2bf(oo[4 * g + 3] * inv) << 16);
      *reinterpret_cast<uint2*>(
          &att_ws[(size_t)(b * 2048 + q0 + L) * 1024 + h * 64 + d0]) = ov;
    }
  }
}

// ---------------- launch ----------------
extern "C" void kernel_launch(void* const* d_in, const int* in_sizes, int n_in,
                              void* d_out, int out_size, void* d_ws, size_t ws_size,
                              hipStream_t stream) {
  (void)in_sizes; (void)n_in; (void)out_size; (void)ws_size;
  const float* x     = (const float*)d_in[0];
  const float* W_qkv = (const float*)d_in[1];
  const float* b_qkv = (const float*)d_in[2];
  const float* W_out = (const float*)d_in[3];
  const float* b_out = (const float*)d_in[4];
  float* out = (float*)d_out;

  char* ws = (char*)d_ws;
  unsigned short* xb    = (unsigned short*)(ws);
  unsigned short* wqkvT = (unsigned short*)(ws + 16777216);
  unsigned short* woutT = (unsigned short*)(ws + 23068672);
  unsigned short* q_ws  = (unsigned short*)(ws + 25165824);
  unsigned short* k_ws  = (unsigned short*)(ws + 41943040);
  unsigned short* vt_ws = (unsigned short*)(ws + 58720256);
  unsigned short* attb  = (unsigned short*)(ws + 75497472);

  prep_k<<<9216, 256, 0, stream>>>(x, xb, W_qkv, wqkvT, W_out, woutT);

  dim3 g1(64, 24);  // proven 4-wave 128x128 structure for the big GEMM
  gemm_bt<0, 128><<<g1, 256, 0, stream>>>(xb, wqkvT, b_qkv, nullptr, q_ws, k_ws, vt_ws,
                                          8192, 3072, 1024);

  attn_k<<<1024, 256, 0, stream>>>(q_ws, k_ws, vt_ws, attb);

  dim3 g2(32, 8);   // 8-wave 256x128 structure for the LDS-read-light proj GEMM
  gemm8<1><<<g2, 512, 0, stream>>>(attb, woutT, b_out, out, nullptr, nullptr, nullptr, 1024);
}